// Round 4
// baseline (784.818 us; speedup 1.0000x reference)
//
#include <hip/hip_runtime.h>
#include <stdint.h>

// Problem constants (fixed shapes)
#define TT 8192      // tokens = B*S
#define HH 2048      // hidden dim
#define II 1408      // intermediate dim
#define NE 8         // experts
#define NROWS (TT*2) // (token, slot) rows = 16384
#define BM 128       // row tile
#define BK 64        // k tile
#define MAX_SLOTS 144
#define NKT_GU (HH/BK)   // 32
#define NKT_DN (II/BK)   // 22

typedef unsigned short u16;
typedef __attribute__((ext_vector_type(8))) __bf16 bhalf8;
typedef __attribute__((ext_vector_type(4))) float f32x4;
typedef __attribute__((ext_vector_type(4))) float float4v;
typedef __attribute__((ext_vector_type(4))) int int4v;

__device__ __forceinline__ u16 f2bf(float f) {
  union { float f; unsigned u; } v; v.f = f;
  return (u16)((v.u + 0x7FFFu + ((v.u >> 16) & 1u)) >> 16);  // RNE
}

__device__ __forceinline__ void gld16(const void* g, void* l) {
  __builtin_amdgcn_global_load_lds(
      (const __attribute__((address_space(1))) unsigned int*)g,
      (__attribute__((address_space(3))) unsigned int*)l, 16, 0, 0);
}

// ---------------- hidden_states fp32 -> bf16 ----------------
__global__ __launch_bounds__(256) void k_cvt_hs(const float* __restrict__ in,
                                                u16* __restrict__ out) {
  size_t i = ((size_t)blockIdx.x * 256 + threadIdx.x) * 8;
  float4v a = *(const float4v*)(in + i);
  float4v b = *(const float4v*)(in + i + 4);
  u16 o[8];
  o[0] = f2bf(a.x); o[1] = f2bf(a.y); o[2] = f2bf(a.z); o[3] = f2bf(a.w);
  o[4] = f2bf(b.x); o[5] = f2bf(b.y); o[6] = f2bf(b.z); o[7] = f2bf(b.w);
  *(int4v*)(out + i) = *(const int4v*)o;
}

// ------- weight fp32 [E][R][C] -> bf16 transposed [E][C][R] -------
__global__ __launch_bounds__(256) void k_tconv(const float* __restrict__ in,
                                               u16* __restrict__ out,
                                               int R, int C) {
  __shared__ float t[64][65];
  int e = blockIdx.z;
  int r0 = blockIdx.y * 64, c0 = blockIdx.x * 64;
  const float* ip = in + (size_t)e * R * C;
  u16* op = out + (size_t)e * R * C;
  int tid = threadIdx.x;
  int rr = tid >> 4, c4 = (tid & 15) * 4;
#pragma unroll
  for (int j = 0; j < 4; ++j) {
    float4v v = *(const float4v*)&ip[(size_t)(r0 + rr + 16 * j) * C + c0 + c4];
    t[rr + 16 * j][c4 + 0] = v.x;
    t[rr + 16 * j][c4 + 1] = v.y;
    t[rr + 16 * j][c4 + 2] = v.z;
    t[rr + 16 * j][c4 + 3] = v.w;
  }
  __syncthreads();
  int cc = tid >> 2, rb = (tid & 3) * 16;
  u16 buf[16];
#pragma unroll
  for (int i = 0; i < 16; ++i) buf[i] = f2bf(t[rb + i][cc]);
  u16* p = op + (size_t)(c0 + cc) * R + r0 + rb;
  *(int4v*)p = *(const int4v*)&buf[0];
  *(int4v*)(p + 8) = *(const int4v*)&buf[8];
}

// ---------------- routing: gather rows by expert ----------------
__global__ __launch_bounds__(256) void k_route(const int* __restrict__ sel,
                                               const float* __restrict__ rw,
                                               int* __restrict__ token_idx,
                                               float* __restrict__ wrow,
                                               int* __restrict__ s_e,
                                               int* __restrict__ s_rs,
                                               int* __restrict__ s_rows) {
  __shared__ int cnt[NE], offs[NE + 1], cursor[NE];
  int tid = threadIdx.x;
  if (tid < NE) cnt[tid] = 0;
  __syncthreads();
  for (int i = tid; i < NROWS; i += 256) atomicAdd(&cnt[sel[i]], 1);
  __syncthreads();
  if (tid == 0) {
    int o = 0;
    for (int e = 0; e < NE; ++e) { offs[e] = o; o += cnt[e]; }
    offs[NE] = o;
    int ns = 0;
    for (int e = 0; e < NE; ++e) {
      for (int t = 0; t < cnt[e]; t += BM) {
        s_e[ns] = e;
        s_rs[ns] = offs[e] + t;
        s_rows[ns] = (cnt[e] - t < BM) ? (cnt[e] - t) : BM;
        ns++;
      }
    }
    for (; ns < MAX_SLOTS; ++ns) s_rows[ns] = 0;
  }
  __syncthreads();
  if (tid < NE) cursor[tid] = offs[tid];
  __syncthreads();
  for (int i = tid; i < NROWS; i += 256) {
    int e = sel[i];
    int r = atomicAdd(&cursor[e], 1);
    token_idx[r] = i >> 1;   // token id
    wrow[r] = rw[i];         // routing weight for this slot
  }
}

// ---------------- gate/up GEMM + SwiGLU epilogue ----------------
// m97 structure: single-buffered LDS, stage -> barrier -> MFMA -> barrier.
// Grid: x = ytile (fast-varying), y = slot -> A-tile L2-resident per slot,
// expert B-panels L3-resident across the expert's consecutive slots.
__global__ __launch_bounds__(256, 5) void k_gu(const u16* __restrict__ hsb,
                                               const u16* __restrict__ gwt,
                                               const u16* __restrict__ uwt,
                                               const int* __restrict__ token_idx,
                                               const float* __restrict__ wrow,
                                               const int* __restrict__ s_e,
                                               const int* __restrict__ s_rs,
                                               const int* __restrict__ s_rows,
                                               u16* __restrict__ act) {
  int slot = blockIdx.y;
  int nrows = s_rows[slot];
  if (nrows == 0) return;
  int e = s_e[slot];
  int row0 = s_rs[slot];
  int i0 = blockIdx.x * 64;

  __shared__ alignas(16) u16 As[BM][BK];   // 16 KB
  __shared__ alignas(16) u16 Bg[64][BK];   // 8 KB
  __shared__ alignas(16) u16 Bu[64][BK];   // 8 KB  -> 32 KB total

  int tid = threadIdx.x;
  int lane = tid & 63;
  int wid = tid >> 6;
  int l8 = lane >> 3;          // row within 8-row group
  int c8 = lane & 7;           // 16B chunk within row
  int cs = c8 ^ l8;            // swizzled source chunk (dest LDS linear, rule #21)

  // A staging sources: wave wid covers rows wid*32 + j*8 + l8
  const u16* agp[4];
#pragma unroll
  for (int j = 0; j < 4; ++j) {
    int gr = row0 + wid * 32 + j * 8 + l8;
    if (gr > NROWS - 1) gr = NROWS - 1;
    int tok = token_idx[gr];
    agp[j] = hsb + (size_t)tok * HH + cs * 8;
  }
  // B staging: rows wid*16 + j*8 + l8 of the [64][HH] panel at i0
  const u16* ggp[2]; const u16* ugp[2];
#pragma unroll
  for (int j = 0; j < 2; ++j) {
    size_t off = ((size_t)e * II + i0 + wid * 16 + j * 8 + l8) * HH + cs * 8;
    ggp[j] = gwt + off;
    ugp[j] = uwt + off;
  }

  int wm = wid >> 1, wn = wid & 1;
  int l15 = lane & 15, l16 = lane >> 4;

  f32x4 accg[4][2], accu[4][2];
#pragma unroll
  for (int a = 0; a < 4; ++a)
#pragma unroll
    for (int b = 0; b < 2; ++b) { accg[a][b] = (f32x4)0.0f; accu[a][b] = (f32x4)0.0f; }

  for (int kt = 0; kt < NKT_GU; ++kt) {
    int k0 = kt * BK;
#pragma unroll
    for (int j = 0; j < 4; ++j) gld16(agp[j] + k0, &As[wid * 32 + j * 8][0]);
#pragma unroll
    for (int j = 0; j < 2; ++j) {
      gld16(ggp[j] + k0, &Bg[wid * 16 + j * 8][0]);
      gld16(ugp[j] + k0, &Bu[wid * 16 + j * 8][0]);
    }
    __syncthreads();
#pragma unroll
    for (int ks = 0; ks < 2; ++ks) {
      bhalf8 af[4], bgf[2], buf_[2];
#pragma unroll
      for (int mf = 0; mf < 4; ++mf) {
        int row = wm * 64 + mf * 16 + l15;
        int c = (ks * 4 + l16) ^ (row & 7);
        af[mf] = *(const bhalf8*)&As[row][c * 8];
      }
#pragma unroll
      for (int nf = 0; nf < 2; ++nf) {
        int row = wn * 32 + nf * 16 + l15;
        int c = (ks * 4 + l16) ^ (row & 7);
        bgf[nf] = *(const bhalf8*)&Bg[row][c * 8];
        buf_[nf] = *(const bhalf8*)&Bu[row][c * 8];
      }
#pragma unroll
      for (int mf = 0; mf < 4; ++mf)
#pragma unroll
        for (int nf = 0; nf < 2; ++nf) {
          accg[mf][nf] = __builtin_amdgcn_mfma_f32_16x16x32_bf16(af[mf], bgf[nf], accg[mf][nf], 0, 0, 0);
          accu[mf][nf] = __builtin_amdgcn_mfma_f32_16x16x32_bf16(af[mf], buf_[nf], accu[mf][nf], 0, 0, 0);
        }
    }
    __syncthreads();
  }

  // epilogue: act = w * silu(g) * u
#pragma unroll
  for (int mf = 0; mf < 4; ++mf) {
#pragma unroll
    for (int j = 0; j < 4; ++j) {
      int lm = wm * 64 + mf * 16 + l16 * 4 + j;
      if (lm < nrows) {
        int gr = row0 + lm;
        float w = wrow[gr];
        size_t base = (size_t)gr * II + i0 + wn * 32 + l15;
#pragma unroll
        for (int nf = 0; nf < 2; ++nf) {
          float g = accg[mf][nf][j];
          float u = accu[mf][nf][j];
          float s = g / (1.0f + __expf(-g));
          act[base + nf * 16] = f2bf(s * u * w);
        }
      }
    }
  }
}

// ---------------- down GEMM + scatter-add epilogue ----------------
// A: act rows [*][II]; B: dwt [E][HH][II] (pre-transposed); out += per-slot result
__global__ __launch_bounds__(256, 6) void k_down(const u16* __restrict__ act,
                                                 const u16* __restrict__ dwt,
                                                 const int* __restrict__ token_idx,
                                                 const int* __restrict__ s_e,
                                                 const int* __restrict__ s_rs,
                                                 const int* __restrict__ s_rows,
                                                 float* __restrict__ out) {
  int slot = blockIdx.y;
  int nrows = s_rows[slot];
  if (nrows == 0) return;
  int e = s_e[slot];
  int row0 = s_rs[slot];
  int h0 = blockIdx.x * 64;

  __shared__ alignas(16) u16 As[BM][BK];   // 16 KB
  __shared__ alignas(16) u16 Bs[64][BK];   // 8 KB  -> 24 KB total

  int tid = threadIdx.x;
  int lane = tid & 63;
  int wid = tid >> 6;
  int l8 = lane >> 3;
  int c8 = lane & 7;
  int cs = c8 ^ l8;

  const u16* agp[4];
#pragma unroll
  for (int j = 0; j < 4; ++j) {
    int gr = row0 + wid * 32 + j * 8 + l8;
    if (gr > NROWS - 1) gr = NROWS - 1;
    agp[j] = act + (size_t)gr * II + cs * 8;
  }
  const u16* bgp[2];
#pragma unroll
  for (int j = 0; j < 2; ++j)
    bgp[j] = dwt + ((size_t)e * HH + h0 + wid * 16 + j * 8 + l8) * II + cs * 8;

  int wm = wid >> 1, wn = wid & 1;
  int l15 = lane & 15, l16 = lane >> 4;

  f32x4 acc[4][2];
#pragma unroll
  for (int a = 0; a < 4; ++a)
#pragma unroll
    for (int b = 0; b < 2; ++b) acc[a][b] = (f32x4)0.0f;

  for (int kt = 0; kt < NKT_DN; ++kt) {
    int k0 = kt * BK;
#pragma unroll
    for (int j = 0; j < 4; ++j) gld16(agp[j] + k0, &As[wid * 32 + j * 8][0]);
#pragma unroll
    for (int j = 0; j < 2; ++j) gld16(bgp[j] + k0, &Bs[wid * 16 + j * 8][0]);
    __syncthreads();
#pragma unroll
    for (int ks = 0; ks < 2; ++ks) {
      bhalf8 af[4], bf[2];
#pragma unroll
      for (int mf = 0; mf < 4; ++mf) {
        int row = wm * 64 + mf * 16 + l15;
        int c = (ks * 4 + l16) ^ (row & 7);
        af[mf] = *(const bhalf8*)&As[row][c * 8];
      }
#pragma unroll
      for (int nf = 0; nf < 2; ++nf) {
        int row = wn * 32 + nf * 16 + l15;
        int c = (ks * 4 + l16) ^ (row & 7);
        bf[nf] = *(const bhalf8*)&Bs[row][c * 8];
      }
#pragma unroll
      for (int mf = 0; mf < 4; ++mf)
#pragma unroll
        for (int nf = 0; nf < 2; ++nf)
          acc[mf][nf] = __builtin_amdgcn_mfma_f32_16x16x32_bf16(af[mf], bf[nf], acc[mf][nf], 0, 0, 0);
    }
    __syncthreads();
  }

#pragma unroll
  for (int mf = 0; mf < 4; ++mf) {
#pragma unroll
    for (int j = 0; j < 4; ++j) {
      int lm = wm * 64 + mf * 16 + l16 * 4 + j;
      if (lm < nrows) {
        int tok = token_idx[row0 + lm];
        size_t base = (size_t)tok * HH + h0 + wn * 32 + l15;
#pragma unroll
        for (int nf = 0; nf < 2; ++nf)
          atomicAdd(&out[base + nf * 16], acc[mf][nf][j]);
      }
    }
  }
}

extern "C" void kernel_launch(void* const* d_in, const int* in_sizes, int n_in,
                              void* d_out, int out_size, void* d_ws, size_t ws_size,
                              hipStream_t stream) {
  const int* sel = (const int*)d_in[0];
  const float* hs = (const float*)d_in[1];
  const float* rw = (const float*)d_in[2];
  const float* gw = (const float*)d_in[3];
  const float* uw = (const float*)d_in[4];
  const float* dw = (const float*)d_in[5];
  float* out = (float*)d_out;

  char* ws = (char*)d_ws;
  size_t o = 0;
  u16* hsb = (u16*)(ws + o); o += (size_t)TT * HH * 2;           // 32 MB
  u16* gwt = (u16*)(ws + o); o += (size_t)NE * HH * II * 2;      // 44 MB
  u16* uwt = (u16*)(ws + o); o += (size_t)NE * HH * II * 2;      // 44 MB
  u16* dwt = (u16*)(ws + o); o += (size_t)NE * HH * II * 2;      // 44 MB
  u16* act = (u16*)(ws + o); o += (size_t)NROWS * II * 2;        // 44 MB
  int* token_idx = (int*)(ws + o); o += (size_t)NROWS * 4;
  float* wrow = (float*)(ws + o); o += (size_t)NROWS * 4;
  int* s_e = (int*)(ws + o); o += MAX_SLOTS * 4;
  int* s_rs = (int*)(ws + o); o += MAX_SLOTS * 4;
  int* s_rows = (int*)(ws + o); o += MAX_SLOTS * 4;
  (void)ws_size; (void)in_sizes; (void)n_in; (void)out_size;

  // fp32 -> bf16 conversions (+ weight transpose to [N][K])
  k_cvt_hs<<<(TT * HH) / 2048, 256, 0, stream>>>(hs, hsb);
  dim3 g1(II / 64, HH / 64, NE);
  k_tconv<<<g1, 256, 0, stream>>>(gw, gwt, HH, II);
  k_tconv<<<g1, 256, 0, stream>>>(uw, uwt, HH, II);
  dim3 g2(HH / 64, II / 64, NE);
  k_tconv<<<g2, 256, 0, stream>>>(dw, dwt, II, HH);

  // routing + zero output (both cheap, before the big GEMMs)
  k_route<<<1, 256, 0, stream>>>(sel, rw, token_idx, wrow, s_e, s_rs, s_rows);
  hipMemsetAsync(d_out, 0, (size_t)TT * HH * 4, stream);

  // gate/up GEMM + SwiGLU  (x = ytile fast, y = slot)
  dim3 g3(II / 64, MAX_SLOTS);
  k_gu<<<g3, 256, 0, stream>>>(hsb, gwt, uwt, token_idx, wrow, s_e, s_rs, s_rows, act);

  // down GEMM with scatter-add  (x = ytile fast, y = slot)
  dim3 g4(HH / 64, MAX_SLOTS);
  k_down<<<g4, 256, 0, stream>>>(act, dwt, token_idx, s_e, s_rs, s_rows, out);
}

// Round 5
// 584.780 us; speedup vs baseline: 1.3421x; 1.3421x over previous
//
#include <hip/hip_runtime.h>
#include <stdint.h>

// Problem constants (fixed shapes)
#define TT 8192      // tokens = B*S
#define HH 2048      // hidden dim
#define II 1408      // intermediate dim
#define NE 8         // experts
#define NROWS (TT*2) // (token, slot) rows = 16384
#define BM 128       // row tile
#define BK 64        // k tile
#define MAX_SLOTS 144
#define NKT_GU (HH/BK)   // 32
#define NKT_DN (II/BK)   // 22

typedef unsigned short u16;
typedef __attribute__((ext_vector_type(8))) __bf16 bhalf8;
typedef __attribute__((ext_vector_type(4))) float f32x4;
typedef __attribute__((ext_vector_type(4))) float float4v;
typedef __attribute__((ext_vector_type(4))) int int4v;

__device__ __forceinline__ u16 f2bf(float f) {
  union { float f; unsigned u; } v; v.f = f;
  return (u16)((v.u + 0x7FFFu + ((v.u >> 16) & 1u)) >> 16);  // RNE
}

__device__ __forceinline__ void gld16(const void* g, void* l) {
  __builtin_amdgcn_global_load_lds(
      (const __attribute__((address_space(1))) unsigned int*)g,
      (__attribute__((address_space(3))) unsigned int*)l, 16, 0, 0);
}

// ---------------- hidden_states fp32 -> bf16 ----------------
__global__ __launch_bounds__(256) void k_cvt_hs(const float* __restrict__ in,
                                                u16* __restrict__ out) {
  size_t i = ((size_t)blockIdx.x * 256 + threadIdx.x) * 8;
  float4v a = *(const float4v*)(in + i);
  float4v b = *(const float4v*)(in + i + 4);
  u16 o[8];
  o[0] = f2bf(a.x); o[1] = f2bf(a.y); o[2] = f2bf(a.z); o[3] = f2bf(a.w);
  o[4] = f2bf(b.x); o[5] = f2bf(b.y); o[6] = f2bf(b.z); o[7] = f2bf(b.w);
  *(int4v*)(out + i) = *(const int4v*)o;
}

// ------- weight fp32 [E][R][C] -> bf16 transposed [E][C][R] -------
__global__ __launch_bounds__(256) void k_tconv(const float* __restrict__ in,
                                               u16* __restrict__ out,
                                               int R, int C) {
  __shared__ float t[64][65];
  int e = blockIdx.z;
  int r0 = blockIdx.y * 64, c0 = blockIdx.x * 64;
  const float* ip = in + (size_t)e * R * C;
  u16* op = out + (size_t)e * R * C;
  int tid = threadIdx.x;
  int rr = tid >> 4, c4 = (tid & 15) * 4;
#pragma unroll
  for (int j = 0; j < 4; ++j) {
    float4v v = *(const float4v*)&ip[(size_t)(r0 + rr + 16 * j) * C + c0 + c4];
    t[rr + 16 * j][c4 + 0] = v.x;
    t[rr + 16 * j][c4 + 1] = v.y;
    t[rr + 16 * j][c4 + 2] = v.z;
    t[rr + 16 * j][c4 + 3] = v.w;
  }
  __syncthreads();
  int cc = tid >> 2, rb = (tid & 3) * 16;
  u16 buf[16];
#pragma unroll
  for (int i = 0; i < 16; ++i) buf[i] = f2bf(t[rb + i][cc]);
  u16* p = op + (size_t)(c0 + cc) * R + r0 + rb;
  *(int4v*)p = *(const int4v*)&buf[0];
  *(int4v*)(p + 8) = *(const int4v*)&buf[8];
}

// ---------------- routing: gather rows by expert ----------------
__global__ __launch_bounds__(256) void k_route(const int* __restrict__ sel,
                                               const float* __restrict__ rw,
                                               int* __restrict__ token_idx,
                                               float* __restrict__ wrow,
                                               int* __restrict__ s_e,
                                               int* __restrict__ s_rs,
                                               int* __restrict__ s_rows) {
  __shared__ int cnt[NE], offs[NE + 1], cursor[NE];
  int tid = threadIdx.x;
  if (tid < NE) cnt[tid] = 0;
  __syncthreads();
  for (int i = tid; i < NROWS; i += 256) atomicAdd(&cnt[sel[i]], 1);
  __syncthreads();
  if (tid == 0) {
    int o = 0;
    for (int e = 0; e < NE; ++e) { offs[e] = o; o += cnt[e]; }
    offs[NE] = o;
    int ns = 0;
    for (int e = 0; e < NE; ++e) {
      for (int t = 0; t < cnt[e]; t += BM) {
        s_e[ns] = e;
        s_rs[ns] = offs[e] + t;
        s_rows[ns] = (cnt[e] - t < BM) ? (cnt[e] - t) : BM;
        ns++;
      }
    }
    for (; ns < MAX_SLOTS; ++ns) s_rows[ns] = 0;
  }
  __syncthreads();
  if (tid < NE) cursor[tid] = offs[tid];
  __syncthreads();
  for (int i = tid; i < NROWS; i += 256) {
    int e = sel[i];
    int r = atomicAdd(&cursor[e], 1);
    token_idx[r] = i >> 1;   // token id
    wrow[r] = rw[i];         // routing weight for this slot
  }
}

// ---------------- gate/up GEMM + SwiGLU epilogue ----------------
// m97 structure: single-buffered LDS, stage -> barrier -> MFMA -> barrier.
// Grid: x = ytile (fast-varying), y = slot. launch_bounds (256,4): unified
// VGPR budget 128/wave = 64 arch + 64 acc, exactly fits without spill.
__global__ __launch_bounds__(256, 4) void k_gu(const u16* __restrict__ hsb,
                                               const u16* __restrict__ gwt,
                                               const u16* __restrict__ uwt,
                                               const int* __restrict__ token_idx,
                                               const float* __restrict__ wrow,
                                               const int* __restrict__ s_e,
                                               const int* __restrict__ s_rs,
                                               const int* __restrict__ s_rows,
                                               u16* __restrict__ act) {
  int slot = blockIdx.y;
  int nrows = s_rows[slot];
  if (nrows == 0) return;
  int e = s_e[slot];
  int row0 = s_rs[slot];
  int i0 = blockIdx.x * 64;

  __shared__ alignas(16) u16 As[BM][BK];   // 16 KB
  __shared__ alignas(16) u16 Bg[64][BK];   // 8 KB
  __shared__ alignas(16) u16 Bu[64][BK];   // 8 KB  -> 32 KB total

  int tid = threadIdx.x;
  int lane = tid & 63;
  int wid = tid >> 6;
  int l8 = lane >> 3;          // row within 8-row group
  int c8 = lane & 7;           // 16B chunk within row
  int cs = c8 ^ l8;            // swizzled source chunk (dest LDS linear, rule #21)

  // A staging sources: wave wid covers rows wid*32 + j*8 + l8
  const u16* agp[4];
#pragma unroll
  for (int j = 0; j < 4; ++j) {
    int gr = row0 + wid * 32 + j * 8 + l8;
    if (gr > NROWS - 1) gr = NROWS - 1;
    int tok = token_idx[gr];
    agp[j] = hsb + (size_t)tok * HH + cs * 8;
  }
  // B staging: rows wid*16 + j*8 + l8 of the [64][HH] panel at i0
  const u16* ggp[2]; const u16* ugp[2];
#pragma unroll
  for (int j = 0; j < 2; ++j) {
    size_t off = ((size_t)e * II + i0 + wid * 16 + j * 8 + l8) * HH + cs * 8;
    ggp[j] = gwt + off;
    ugp[j] = uwt + off;
  }

  int wm = wid >> 1, wn = wid & 1;
  int l15 = lane & 15, l16 = lane >> 4;

  f32x4 accg[4][2], accu[4][2];
#pragma unroll
  for (int a = 0; a < 4; ++a)
#pragma unroll
    for (int b = 0; b < 2; ++b) { accg[a][b] = (f32x4)0.0f; accu[a][b] = (f32x4)0.0f; }

  for (int kt = 0; kt < NKT_GU; ++kt) {
    int k0 = kt * BK;
#pragma unroll
    for (int j = 0; j < 4; ++j) gld16(agp[j] + k0, &As[wid * 32 + j * 8][0]);
#pragma unroll
    for (int j = 0; j < 2; ++j) {
      gld16(ggp[j] + k0, &Bg[wid * 16 + j * 8][0]);
      gld16(ugp[j] + k0, &Bu[wid * 16 + j * 8][0]);
    }
    __syncthreads();
#pragma unroll
    for (int ks = 0; ks < 2; ++ks) {
      bhalf8 af[4], bgf[2], buf_[2];
#pragma unroll
      for (int mf = 0; mf < 4; ++mf) {
        int row = wm * 64 + mf * 16 + l15;
        int c = (ks * 4 + l16) ^ (row & 7);
        af[mf] = *(const bhalf8*)&As[row][c * 8];
      }
#pragma unroll
      for (int nf = 0; nf < 2; ++nf) {
        int row = wn * 32 + nf * 16 + l15;
        int c = (ks * 4 + l16) ^ (row & 7);
        bgf[nf] = *(const bhalf8*)&Bg[row][c * 8];
        buf_[nf] = *(const bhalf8*)&Bu[row][c * 8];
      }
#pragma unroll
      for (int mf = 0; mf < 4; ++mf)
#pragma unroll
        for (int nf = 0; nf < 2; ++nf) {
          accg[mf][nf] = __builtin_amdgcn_mfma_f32_16x16x32_bf16(af[mf], bgf[nf], accg[mf][nf], 0, 0, 0);
          accu[mf][nf] = __builtin_amdgcn_mfma_f32_16x16x32_bf16(af[mf], buf_[nf], accu[mf][nf], 0, 0, 0);
        }
    }
    __syncthreads();
  }

  // epilogue: act = w * silu(g) * u
#pragma unroll
  for (int mf = 0; mf < 4; ++mf) {
#pragma unroll
    for (int j = 0; j < 4; ++j) {
      int lm = wm * 64 + mf * 16 + l16 * 4 + j;
      if (lm < nrows) {
        int gr = row0 + lm;
        float w = wrow[gr];
        size_t base = (size_t)gr * II + i0 + wn * 32 + l15;
#pragma unroll
        for (int nf = 0; nf < 2; ++nf) {
          float g = accg[mf][nf][j];
          float u = accu[mf][nf][j];
          float s = g / (1.0f + __expf(-g));
          act[base + nf * 16] = f2bf(s * u * w);
        }
      }
    }
  }
}

// ---------------- down GEMM + scatter-add epilogue ----------------
// A: act rows [*][II]; B: dwt [E][HH][II] (pre-transposed); out += per-slot result
__global__ __launch_bounds__(256, 4) void k_down(const u16* __restrict__ act,
                                                 const u16* __restrict__ dwt,
                                                 const int* __restrict__ token_idx,
                                                 const int* __restrict__ s_e,
                                                 const int* __restrict__ s_rs,
                                                 const int* __restrict__ s_rows,
                                                 float* __restrict__ out) {
  int slot = blockIdx.y;
  int nrows = s_rows[slot];
  if (nrows == 0) return;
  int e = s_e[slot];
  int row0 = s_rs[slot];
  int h0 = blockIdx.x * 64;

  __shared__ alignas(16) u16 As[BM][BK];   // 16 KB
  __shared__ alignas(16) u16 Bs[64][BK];   // 8 KB  -> 24 KB total

  int tid = threadIdx.x;
  int lane = tid & 63;
  int wid = tid >> 6;
  int l8 = lane >> 3;
  int c8 = lane & 7;
  int cs = c8 ^ l8;

  const u16* agp[4];
#pragma unroll
  for (int j = 0; j < 4; ++j) {
    int gr = row0 + wid * 32 + j * 8 + l8;
    if (gr > NROWS - 1) gr = NROWS - 1;
    agp[j] = act + (size_t)gr * II + cs * 8;
  }
  const u16* bgp[2];
#pragma unroll
  for (int j = 0; j < 2; ++j)
    bgp[j] = dwt + ((size_t)e * HH + h0 + wid * 16 + j * 8 + l8) * II + cs * 8;

  int wm = wid >> 1, wn = wid & 1;
  int l15 = lane & 15, l16 = lane >> 4;

  f32x4 acc[4][2];
#pragma unroll
  for (int a = 0; a < 4; ++a)
#pragma unroll
    for (int b = 0; b < 2; ++b) acc[a][b] = (f32x4)0.0f;

  for (int kt = 0; kt < NKT_DN; ++kt) {
    int k0 = kt * BK;
#pragma unroll
    for (int j = 0; j < 4; ++j) gld16(agp[j] + k0, &As[wid * 32 + j * 8][0]);
#pragma unroll
    for (int j = 0; j < 2; ++j) gld16(bgp[j] + k0, &Bs[wid * 16 + j * 8][0]);
    __syncthreads();
#pragma unroll
    for (int ks = 0; ks < 2; ++ks) {
      bhalf8 af[4], bf[2];
#pragma unroll
      for (int mf = 0; mf < 4; ++mf) {
        int row = wm * 64 + mf * 16 + l15;
        int c = (ks * 4 + l16) ^ (row & 7);
        af[mf] = *(const bhalf8*)&As[row][c * 8];
      }
#pragma unroll
      for (int nf = 0; nf < 2; ++nf) {
        int row = wn * 32 + nf * 16 + l15;
        int c = (ks * 4 + l16) ^ (row & 7);
        bf[nf] = *(const bhalf8*)&Bs[row][c * 8];
      }
#pragma unroll
      for (int mf = 0; mf < 4; ++mf)
#pragma unroll
        for (int nf = 0; nf < 2; ++nf)
          acc[mf][nf] = __builtin_amdgcn_mfma_f32_16x16x32_bf16(af[mf], bf[nf], acc[mf][nf], 0, 0, 0);
    }
    __syncthreads();
  }

#pragma unroll
  for (int mf = 0; mf < 4; ++mf) {
#pragma unroll
    for (int j = 0; j < 4; ++j) {
      int lm = wm * 64 + mf * 16 + l16 * 4 + j;
      if (lm < nrows) {
        int tok = token_idx[row0 + lm];
        size_t base = (size_t)tok * HH + h0 + wn * 32 + l15;
#pragma unroll
        for (int nf = 0; nf < 2; ++nf)
          atomicAdd(&out[base + nf * 16], acc[mf][nf][j]);
      }
    }
  }
}

extern "C" void kernel_launch(void* const* d_in, const int* in_sizes, int n_in,
                              void* d_out, int out_size, void* d_ws, size_t ws_size,
                              hipStream_t stream) {
  const int* sel = (const int*)d_in[0];
  const float* hs = (const float*)d_in[1];
  const float* rw = (const float*)d_in[2];
  const float* gw = (const float*)d_in[3];
  const float* uw = (const float*)d_in[4];
  const float* dw = (const float*)d_in[5];
  float* out = (float*)d_out;

  char* ws = (char*)d_ws;
  size_t o = 0;
  u16* hsb = (u16*)(ws + o); o += (size_t)TT * HH * 2;           // 32 MB
  u16* gwt = (u16*)(ws + o); o += (size_t)NE * HH * II * 2;      // 44 MB
  u16* uwt = (u16*)(ws + o); o += (size_t)NE * HH * II * 2;      // 44 MB
  u16* dwt = (u16*)(ws + o); o += (size_t)NE * HH * II * 2;      // 44 MB
  u16* act = (u16*)(ws + o); o += (size_t)NROWS * II * 2;        // 44 MB
  int* token_idx = (int*)(ws + o); o += (size_t)NROWS * 4;
  float* wrow = (float*)(ws + o); o += (size_t)NROWS * 4;
  int* s_e = (int*)(ws + o); o += MAX_SLOTS * 4;
  int* s_rs = (int*)(ws + o); o += MAX_SLOTS * 4;
  int* s_rows = (int*)(ws + o); o += MAX_SLOTS * 4;
  (void)ws_size; (void)in_sizes; (void)n_in; (void)out_size;

  // fp32 -> bf16 conversions (+ weight transpose to [N][K])
  k_cvt_hs<<<(TT * HH) / 2048, 256, 0, stream>>>(hs, hsb);
  dim3 g1(II / 64, HH / 64, NE);
  k_tconv<<<g1, 256, 0, stream>>>(gw, gwt, HH, II);
  k_tconv<<<g1, 256, 0, stream>>>(uw, uwt, HH, II);
  dim3 g2(HH / 64, II / 64, NE);
  k_tconv<<<g2, 256, 0, stream>>>(dw, dwt, II, HH);

  // routing + zero output (both cheap, before the big GEMMs)
  k_route<<<1, 256, 0, stream>>>(sel, rw, token_idx, wrow, s_e, s_rs, s_rows);
  hipMemsetAsync(d_out, 0, (size_t)TT * HH * 4, stream);

  // gate/up GEMM + SwiGLU  (x = ytile fast, y = slot)
  dim3 g3(II / 64, MAX_SLOTS);
  k_gu<<<g3, 256, 0, stream>>>(hsb, gwt, uwt, token_idx, wrow, s_e, s_rs, s_rows, act);

  // down GEMM with scatter-add  (x = ytile fast, y = slot)
  dim3 g4(HH / 64, MAX_SLOTS);
  k_down<<<g4, 256, 0, stream>>>(act, dwt, token_idx, s_e, s_rs, s_rows, out);
}

// Round 6
// 574.736 us; speedup vs baseline: 1.3655x; 1.0175x over previous
//
#include <hip/hip_runtime.h>
#include <stdint.h>

// Problem constants (fixed shapes)
#define TT 8192      // tokens = B*S
#define HH 2048      // hidden dim
#define II 1408      // intermediate dim
#define NE 8         // experts
#define NROWS (TT*2) // (token, slot) rows = 16384
#define BM 128       // row tile
#define BK 64        // k tile
#define MAX_SLOTS 144
#define NKT_GU (HH/BK)   // 32
#define NKT_DN (II/BK)   // 22
#define NYT_GU (II/64)   // 22  N-tiles in k_gu
#define NYT_DN (HH/64)   // 32  N-tiles in k_down
#define SLOTS_PER_XCD (MAX_SLOTS/8)  // 18

typedef unsigned short u16;
typedef __attribute__((ext_vector_type(8))) __bf16 bhalf8;
typedef __attribute__((ext_vector_type(4))) float f32x4;
typedef __attribute__((ext_vector_type(4))) float float4v;
typedef __attribute__((ext_vector_type(4))) int int4v;

__device__ __forceinline__ u16 f2bf(float f) {
  union { float f; unsigned u; } v; v.f = f;
  return (u16)((v.u + 0x7FFFu + ((v.u >> 16) & 1u)) >> 16);  // RNE
}

__device__ __forceinline__ void gld16(const void* g, void* l) {
  __builtin_amdgcn_global_load_lds(
      (const __attribute__((address_space(1))) unsigned int*)g,
      (__attribute__((address_space(3))) unsigned int*)l, 16, 0, 0);
}

// ---------------- hidden_states fp32 -> bf16 ----------------
__global__ __launch_bounds__(256) void k_cvt_hs(const float* __restrict__ in,
                                                u16* __restrict__ out) {
  size_t i = ((size_t)blockIdx.x * 256 + threadIdx.x) * 8;
  float4v a = *(const float4v*)(in + i);
  float4v b = *(const float4v*)(in + i + 4);
  u16 o[8];
  o[0] = f2bf(a.x); o[1] = f2bf(a.y); o[2] = f2bf(a.z); o[3] = f2bf(a.w);
  o[4] = f2bf(b.x); o[5] = f2bf(b.y); o[6] = f2bf(b.z); o[7] = f2bf(b.w);
  *(int4v*)(out + i) = *(const int4v*)o;
}

// ------- weight fp32 [E][R][C] -> bf16 transposed [E][C][R] -------
__global__ __launch_bounds__(256) void k_tconv(const float* __restrict__ in,
                                               u16* __restrict__ out,
                                               int R, int C) {
  __shared__ float t[64][65];
  int e = blockIdx.z;
  int r0 = blockIdx.y * 64, c0 = blockIdx.x * 64;
  const float* ip = in + (size_t)e * R * C;
  u16* op = out + (size_t)e * R * C;
  int tid = threadIdx.x;
  int rr = tid >> 4, c4 = (tid & 15) * 4;
#pragma unroll
  for (int j = 0; j < 4; ++j) {
    float4v v = *(const float4v*)&ip[(size_t)(r0 + rr + 16 * j) * C + c0 + c4];
    t[rr + 16 * j][c4 + 0] = v.x;
    t[rr + 16 * j][c4 + 1] = v.y;
    t[rr + 16 * j][c4 + 2] = v.z;
    t[rr + 16 * j][c4 + 3] = v.w;
  }
  __syncthreads();
  int cc = tid >> 2, rb = (tid & 3) * 16;
  u16 buf[16];
#pragma unroll
  for (int i = 0; i < 16; ++i) buf[i] = f2bf(t[rb + i][cc]);
  u16* p = op + (size_t)(c0 + cc) * R + r0 + rb;
  *(int4v*)p = *(const int4v*)&buf[0];
  *(int4v*)(p + 8) = *(const int4v*)&buf[8];
}

// ---------------- routing: gather rows by expert ----------------
__global__ __launch_bounds__(256) void k_route(const int* __restrict__ sel,
                                               const float* __restrict__ rw,
                                               int* __restrict__ token_idx,
                                               float* __restrict__ wrow,
                                               int* __restrict__ s_e,
                                               int* __restrict__ s_rs,
                                               int* __restrict__ s_rows) {
  __shared__ int cnt[NE], offs[NE + 1], cursor[NE];
  int tid = threadIdx.x;
  if (tid < NE) cnt[tid] = 0;
  __syncthreads();
  for (int i = tid; i < NROWS; i += 256) atomicAdd(&cnt[sel[i]], 1);
  __syncthreads();
  if (tid == 0) {
    int o = 0;
    for (int e = 0; e < NE; ++e) { offs[e] = o; o += cnt[e]; }
    offs[NE] = o;
    int ns = 0;
    for (int e = 0; e < NE; ++e) {
      for (int t = 0; t < cnt[e]; t += BM) {
        s_e[ns] = e;
        s_rs[ns] = offs[e] + t;
        s_rows[ns] = (cnt[e] - t < BM) ? (cnt[e] - t) : BM;
        ns++;
      }
    }
    for (; ns < MAX_SLOTS; ++ns) s_rows[ns] = 0;
  }
  __syncthreads();
  if (tid < NE) cursor[tid] = offs[tid];
  __syncthreads();
  for (int i = tid; i < NROWS; i += 256) {
    int e = sel[i];
    int r = atomicAdd(&cursor[e], 1);
    token_idx[r] = i >> 1;   // token id
    wrow[r] = rw[i];         // routing weight for this slot
  }
}

// ---------------- gate/up GEMM + SwiGLU epilogue ----------------
// m97 structure: single-buffered LDS, stage -> barrier -> MFMA -> barrier.
// 1D grid, XCD-aware swizzle (T1): xcd = f&7 owns 18 contiguous slots;
// a slot's 22 ytile-blocks are consecutive on ONE XCD -> A-tile fills one L2.
__global__ __launch_bounds__(256, 4) void k_gu(const u16* __restrict__ hsb,
                                               const u16* __restrict__ gwt,
                                               const u16* __restrict__ uwt,
                                               const int* __restrict__ token_idx,
                                               const float* __restrict__ wrow,
                                               const int* __restrict__ s_e,
                                               const int* __restrict__ s_rs,
                                               const int* __restrict__ s_rows,
                                               u16* __restrict__ act) {
  int f = blockIdx.x;
  int xcd = f & 7;
  int pos = f >> 3;                 // 0..395
  int slot = xcd * SLOTS_PER_XCD + pos / NYT_GU;
  int ytile = pos % NYT_GU;
  int nrows = s_rows[slot];
  if (nrows == 0) return;
  int e = s_e[slot];
  int row0 = s_rs[slot];
  int i0 = ytile * 64;

  __shared__ alignas(16) u16 As[BM][BK];   // 16 KB
  __shared__ alignas(16) u16 Bg[64][BK];   // 8 KB
  __shared__ alignas(16) u16 Bu[64][BK];   // 8 KB  -> 32 KB total

  int tid = threadIdx.x;
  int lane = tid & 63;
  int wid = tid >> 6;
  int l8 = lane >> 3;          // row within 8-row group
  int c8 = lane & 7;           // 16B chunk within row
  int cs = c8 ^ l8;            // swizzled source chunk (dest LDS linear, rule #21)

  // A staging sources: wave wid covers rows wid*32 + j*8 + l8
  const u16* agp[4];
#pragma unroll
  for (int j = 0; j < 4; ++j) {
    int gr = row0 + wid * 32 + j * 8 + l8;
    if (gr > NROWS - 1) gr = NROWS - 1;
    int tok = token_idx[gr];
    agp[j] = hsb + (size_t)tok * HH + cs * 8;
  }
  // B staging: rows wid*16 + j*8 + l8 of the [64][HH] panel at i0
  const u16* ggp[2]; const u16* ugp[2];
#pragma unroll
  for (int j = 0; j < 2; ++j) {
    size_t off = ((size_t)e * II + i0 + wid * 16 + j * 8 + l8) * HH + cs * 8;
    ggp[j] = gwt + off;
    ugp[j] = uwt + off;
  }

  int wm = wid >> 1, wn = wid & 1;
  int l15 = lane & 15, l16 = lane >> 4;

  f32x4 accg[4][2], accu[4][2];
#pragma unroll
  for (int a = 0; a < 4; ++a)
#pragma unroll
    for (int b = 0; b < 2; ++b) { accg[a][b] = (f32x4)0.0f; accu[a][b] = (f32x4)0.0f; }

  for (int kt = 0; kt < NKT_GU; ++kt) {
    int k0 = kt * BK;
#pragma unroll
    for (int j = 0; j < 4; ++j) gld16(agp[j] + k0, &As[wid * 32 + j * 8][0]);
#pragma unroll
    for (int j = 0; j < 2; ++j) {
      gld16(ggp[j] + k0, &Bg[wid * 16 + j * 8][0]);
      gld16(ugp[j] + k0, &Bu[wid * 16 + j * 8][0]);
    }
    __syncthreads();
#pragma unroll
    for (int ks = 0; ks < 2; ++ks) {
      bhalf8 af[4], bgf[2], buf_[2];
#pragma unroll
      for (int mf = 0; mf < 4; ++mf) {
        int row = wm * 64 + mf * 16 + l15;
        int c = (ks * 4 + l16) ^ (row & 7);
        af[mf] = *(const bhalf8*)&As[row][c * 8];
      }
#pragma unroll
      for (int nf = 0; nf < 2; ++nf) {
        int row = wn * 32 + nf * 16 + l15;
        int c = (ks * 4 + l16) ^ (row & 7);
        bgf[nf] = *(const bhalf8*)&Bg[row][c * 8];
        buf_[nf] = *(const bhalf8*)&Bu[row][c * 8];
      }
#pragma unroll
      for (int mf = 0; mf < 4; ++mf)
#pragma unroll
        for (int nf = 0; nf < 2; ++nf) {
          accg[mf][nf] = __builtin_amdgcn_mfma_f32_16x16x32_bf16(af[mf], bgf[nf], accg[mf][nf], 0, 0, 0);
          accu[mf][nf] = __builtin_amdgcn_mfma_f32_16x16x32_bf16(af[mf], buf_[nf], accu[mf][nf], 0, 0, 0);
        }
    }
    __syncthreads();
  }

  // epilogue: act = w * silu(g) * u
#pragma unroll
  for (int mf = 0; mf < 4; ++mf) {
#pragma unroll
    for (int j = 0; j < 4; ++j) {
      int lm = wm * 64 + mf * 16 + l16 * 4 + j;
      if (lm < nrows) {
        int gr = row0 + lm;
        float w = wrow[gr];
        size_t base = (size_t)gr * II + i0 + wn * 32 + l15;
#pragma unroll
        for (int nf = 0; nf < 2; ++nf) {
          float g = accg[mf][nf][j];
          float u = accu[mf][nf][j];
          float s = g / (1.0f + __expf(-g));
          act[base + nf * 16] = f2bf(s * u * w);
        }
      }
    }
  }
}

// ---------------- down GEMM + scatter-add epilogue ----------------
// Same XCD swizzle; A: act rows [*][II]; B: dwt [E][HH][II] (pre-transposed)
__global__ __launch_bounds__(256, 4) void k_down(const u16* __restrict__ act,
                                                 const u16* __restrict__ dwt,
                                                 const int* __restrict__ token_idx,
                                                 const int* __restrict__ s_e,
                                                 const int* __restrict__ s_rs,
                                                 const int* __restrict__ s_rows,
                                                 float* __restrict__ out) {
  int f = blockIdx.x;
  int xcd = f & 7;
  int pos = f >> 3;                 // 0..575
  int slot = xcd * SLOTS_PER_XCD + pos / NYT_DN;
  int ytile = pos % NYT_DN;
  int nrows = s_rows[slot];
  if (nrows == 0) return;
  int e = s_e[slot];
  int row0 = s_rs[slot];
  int h0 = ytile * 64;

  __shared__ alignas(16) u16 As[BM][BK];   // 16 KB
  __shared__ alignas(16) u16 Bs[64][BK];   // 8 KB  -> 24 KB total

  int tid = threadIdx.x;
  int lane = tid & 63;
  int wid = tid >> 6;
  int l8 = lane >> 3;
  int c8 = lane & 7;
  int cs = c8 ^ l8;

  const u16* agp[4];
#pragma unroll
  for (int j = 0; j < 4; ++j) {
    int gr = row0 + wid * 32 + j * 8 + l8;
    if (gr > NROWS - 1) gr = NROWS - 1;
    agp[j] = act + (size_t)gr * II + cs * 8;
  }
  const u16* bgp[2];
#pragma unroll
  for (int j = 0; j < 2; ++j)
    bgp[j] = dwt + ((size_t)e * HH + h0 + wid * 16 + j * 8 + l8) * II + cs * 8;

  int wm = wid >> 1, wn = wid & 1;
  int l15 = lane & 15, l16 = lane >> 4;

  f32x4 acc[4][2];
#pragma unroll
  for (int a = 0; a < 4; ++a)
#pragma unroll
    for (int b = 0; b < 2; ++b) acc[a][b] = (f32x4)0.0f;

  for (int kt = 0; kt < NKT_DN; ++kt) {
    int k0 = kt * BK;
#pragma unroll
    for (int j = 0; j < 4; ++j) gld16(agp[j] + k0, &As[wid * 32 + j * 8][0]);
#pragma unroll
    for (int j = 0; j < 2; ++j) gld16(bgp[j] + k0, &Bs[wid * 16 + j * 8][0]);
    __syncthreads();
#pragma unroll
    for (int ks = 0; ks < 2; ++ks) {
      bhalf8 af[4], bf[2];
#pragma unroll
      for (int mf = 0; mf < 4; ++mf) {
        int row = wm * 64 + mf * 16 + l15;
        int c = (ks * 4 + l16) ^ (row & 7);
        af[mf] = *(const bhalf8*)&As[row][c * 8];
      }
#pragma unroll
      for (int nf = 0; nf < 2; ++nf) {
        int row = wn * 32 + nf * 16 + l15;
        int c = (ks * 4 + l16) ^ (row & 7);
        bf[nf] = *(const bhalf8*)&Bs[row][c * 8];
      }
#pragma unroll
      for (int mf = 0; mf < 4; ++mf)
#pragma unroll
        for (int nf = 0; nf < 2; ++nf)
          acc[mf][nf] = __builtin_amdgcn_mfma_f32_16x16x32_bf16(af[mf], bf[nf], acc[mf][nf], 0, 0, 0);
    }
    __syncthreads();
  }

#pragma unroll
  for (int mf = 0; mf < 4; ++mf) {
#pragma unroll
    for (int j = 0; j < 4; ++j) {
      int lm = wm * 64 + mf * 16 + l16 * 4 + j;
      if (lm < nrows) {
        int tok = token_idx[row0 + lm];
        size_t base = (size_t)tok * HH + h0 + wn * 32 + l15;
#pragma unroll
        for (int nf = 0; nf < 2; ++nf)
          atomicAdd(&out[base + nf * 16], acc[mf][nf][j]);
      }
    }
  }
}

extern "C" void kernel_launch(void* const* d_in, const int* in_sizes, int n_in,
                              void* d_out, int out_size, void* d_ws, size_t ws_size,
                              hipStream_t stream) {
  const int* sel = (const int*)d_in[0];
  const float* hs = (const float*)d_in[1];
  const float* rw = (const float*)d_in[2];
  const float* gw = (const float*)d_in[3];
  const float* uw = (const float*)d_in[4];
  const float* dw = (const float*)d_in[5];
  float* out = (float*)d_out;

  char* ws = (char*)d_ws;
  size_t o = 0;
  u16* hsb = (u16*)(ws + o); o += (size_t)TT * HH * 2;           // 32 MB
  u16* gwt = (u16*)(ws + o); o += (size_t)NE * HH * II * 2;      // 44 MB
  u16* uwt = (u16*)(ws + o); o += (size_t)NE * HH * II * 2;      // 44 MB
  u16* dwt = (u16*)(ws + o); o += (size_t)NE * HH * II * 2;      // 44 MB
  u16* act = (u16*)(ws + o); o += (size_t)NROWS * II * 2;        // 44 MB
  int* token_idx = (int*)(ws + o); o += (size_t)NROWS * 4;
  float* wrow = (float*)(ws + o); o += (size_t)NROWS * 4;
  int* s_e = (int*)(ws + o); o += MAX_SLOTS * 4;
  int* s_rs = (int*)(ws + o); o += MAX_SLOTS * 4;
  int* s_rows = (int*)(ws + o); o += MAX_SLOTS * 4;
  (void)ws_size; (void)in_sizes; (void)n_in; (void)out_size;

  // fp32 -> bf16 conversions (+ weight transpose to [N][K])
  k_cvt_hs<<<(TT * HH) / 2048, 256, 0, stream>>>(hs, hsb);
  dim3 g1(II / 64, HH / 64, NE);
  k_tconv<<<g1, 256, 0, stream>>>(gw, gwt, HH, II);
  k_tconv<<<g1, 256, 0, stream>>>(uw, uwt, HH, II);
  dim3 g2(HH / 64, II / 64, NE);
  k_tconv<<<g2, 256, 0, stream>>>(dw, dwt, II, HH);

  // routing + zero output (both cheap, before the big GEMMs)
  k_route<<<1, 256, 0, stream>>>(sel, rw, token_idx, wrow, s_e, s_rs, s_rows);
  hipMemsetAsync(d_out, 0, (size_t)TT * HH * 4, stream);

  // gate/up GEMM + SwiGLU  (1D grid, XCD swizzle)
  k_gu<<<MAX_SLOTS * NYT_GU, 256, 0, stream>>>(hsb, gwt, uwt, token_idx, wrow,
                                               s_e, s_rs, s_rows, act);

  // down GEMM with scatter-add  (1D grid, XCD swizzle)
  k_down<<<MAX_SLOTS * NYT_DN, 256, 0, stream>>>(act, dwt, token_idx,
                                                 s_e, s_rs, s_rows, out);
}